// Round 2
// baseline (132.167 us; speedup 1.0000x reference)
//
#include <hip/hip_runtime.h>
#include <hip/hip_bf16.h>

typedef __attribute__((ext_vector_type(8))) short bf16x8;
typedef __attribute__((ext_vector_type(4))) float f32x4;

#define NPIX 6272          // 2*56*56
#define HW 56
#define HEADS 8
#define HD 32
#define KW 7
#define KK 49
#define DIM 256

__device__ inline float bf2f(short u) {
    union { unsigned int i; float f; } x;
    x.i = ((unsigned int)(unsigned short)u) << 16;
    return x.f;
}
__device__ inline short f2bf(float f) {
    __hip_bfloat16 h = __float2bfloat16(f);
    return *(short*)&h;
}

// ---------------- Projection GEMM: Y = X @ W^T + b  (optionally * scale) ---
// X: [NPIX][256] f32, W: [256][256] f32 (row o = weights over d),
// Y: [NPIX][256] bf16 (workspace).  One block = 64 rows, 4 waves * 16 rows.
__global__ __launch_bounds__(256) void proj_kernel(
    const float* __restrict__ X,
    const float* __restrict__ Wq,
    const float* __restrict__ Wk,
    const float* __restrict__ Wv,
    const float* __restrict__ Bq,
    const float* __restrict__ Bk,
    const float* __restrict__ Bv,
    __hip_bfloat16* __restrict__ Qo,
    __hip_bfloat16* __restrict__ Ko,
    __hip_bfloat16* __restrict__ Vo)
{
    const int wave = threadIdx.x >> 6;
    const int lane = threadIdx.x & 63;
    const int l15 = lane & 15;
    const int hi  = lane >> 4;          // 0..3
    const int row0 = blockIdx.x * 64 + wave * 16;

    const float* W;
    const float* Bi;
    __hip_bfloat16* Y;
    float scale;
    if (blockIdx.y == 0)      { W = Wq; Bi = Bq; Y = Qo; scale = 0.17677669529663687f; }
    else if (blockIdx.y == 1) { W = Wk; Bi = Bk; Y = Ko; scale = 1.0f; }
    else                      { W = Wv; Bi = Bv; Y = Vo; scale = 1.0f; }

    f32x4 acc[16];
    #pragma unroll
    for (int c = 0; c < 16; ++c) acc[c] = (f32x4){0.f, 0.f, 0.f, 0.f};

    const float* xrow = X + (size_t)(row0 + l15) * DIM;

    #pragma unroll
    for (int kk = 0; kk < 8; ++kk) {
        const float* ap = xrow + kk * 32 + hi * 8;
        float4 a0 = *(const float4*)(ap);
        float4 a1 = *(const float4*)(ap + 4);
        bf16x8 a;
        a[0]=f2bf(a0.x); a[1]=f2bf(a0.y); a[2]=f2bf(a0.z); a[3]=f2bf(a0.w);
        a[4]=f2bf(a1.x); a[5]=f2bf(a1.y); a[6]=f2bf(a1.z); a[7]=f2bf(a1.w);
        #pragma unroll
        for (int c = 0; c < 16; ++c) {
            const float* bp = W + (size_t)(c * 16 + l15) * DIM + kk * 32 + hi * 8;
            float4 b0 = *(const float4*)(bp);
            float4 b1 = *(const float4*)(bp + 4);
            bf16x8 bfr;
            bfr[0]=f2bf(b0.x); bfr[1]=f2bf(b0.y); bfr[2]=f2bf(b0.z); bfr[3]=f2bf(b0.w);
            bfr[4]=f2bf(b1.x); bfr[5]=f2bf(b1.y); bfr[6]=f2bf(b1.z); bfr[7]=f2bf(b1.w);
            acc[c] = __builtin_amdgcn_mfma_f32_16x16x32_bf16(a, bfr, acc[c], 0, 0, 0);
        }
    }

    #pragma unroll
    for (int c = 0; c < 16; ++c) {
        const int col = c * 16 + l15;
        const float bv = Bi[col];
        #pragma unroll
        for (int r = 0; r < 4; ++r) {
            const int row = row0 + hi * 4 + r;
            float v = (acc[c][r] + bv) * scale;
            Y[(size_t)row * DIM + col] = __float2bfloat16(v);
        }
    }
}

// ---------------- Neighborhood attention -----------------------------------
// One thread per (b, i, j, head); head fastest for coalescing.
__global__ __launch_bounds__(256) void nattn_kernel(
    const __hip_bfloat16* __restrict__ Q,   // [B][56][56][256] bf16 (ws)
    const __hip_bfloat16* __restrict__ K,
    const __hip_bfloat16* __restrict__ V,
    const float* __restrict__ rpb,          // [8][13][13] f32
    float* __restrict__ out)                // [B][56][56][256] f32
{
    const int t = blockIdx.x * 256 + threadIdx.x;   // < 50176
    const int head = t & 7;
    const int pix  = t >> 3;         // b*56*56 + i*56 + j
    const int j = pix % HW;
    const int i = (pix / HW) % HW;
    const int b = pix / (HW * HW);

    const int si = min(max(i - 3, 0), HW - KW);
    const int sj = min(max(j - 3, 0), HW - KW);

    const size_t base = (size_t)pix * DIM + head * HD;

    // load q -> f32 regs
    float qf[HD];
    #pragma unroll
    for (int p = 0; p < 4; ++p) {
        bf16x8 qv = *(const bf16x8*)((const short*)Q + base + p * 8);
        #pragma unroll
        for (int e = 0; e < 8; ++e) qf[p * 8 + e] = bf2f(qv[e]);
    }

    // scores
    float sc[KK];
    const float* rb = rpb + head * 169;
    #pragma unroll
    for (int a = 0; a < KW; ++a) {
        const int ki = si + a;
        const int pbi = ki - i + (KW - 1);
        const short* krow = (const short*)K + ((size_t)((b * HW + ki) * HW + sj) * DIM + head * HD);
        #pragma unroll
        for (int c = 0; c < KW; ++c) {
            const short* kp = krow + c * DIM;
            float s = 0.f;
            #pragma unroll
            for (int p = 0; p < 4; ++p) {
                bf16x8 kv = *(const bf16x8*)(kp + p * 8);
                #pragma unroll
                for (int e = 0; e < 8; ++e) s += qf[p * 8 + e] * bf2f(kv[e]);
            }
            const int pbj = sj + c - j + (KW - 1);
            sc[a * KW + c] = s + rb[pbi * 13 + pbj];
        }
    }

    // softmax (numerically stable, in regs)
    float mx = sc[0];
    #pragma unroll
    for (int n = 1; n < KK; ++n) mx = fmaxf(mx, sc[n]);
    float sum = 0.f;
    #pragma unroll
    for (int n = 0; n < KK; ++n) { sc[n] = __expf(sc[n] - mx); sum += sc[n]; }
    const float inv = 1.f / sum;

    // ctx = probs . V
    float ctx[HD];
    #pragma unroll
    for (int d = 0; d < HD; ++d) ctx[d] = 0.f;
    #pragma unroll
    for (int a = 0; a < KW; ++a) {
        const int ki = si + a;
        const short* vrow = (const short*)V + ((size_t)((b * HW + ki) * HW + sj) * DIM + head * HD);
        #pragma unroll
        for (int c = 0; c < KW; ++c) {
            const short* vp = vrow + c * DIM;
            const float w = sc[a * KW + c];
            #pragma unroll
            for (int p = 0; p < 4; ++p) {
                bf16x8 vv = *(const bf16x8*)(vp + p * 8);
                #pragma unroll
                for (int e = 0; e < 8; ++e) ctx[p * 8 + e] += w * bf2f(vv[e]);
            }
        }
    }

    // store f32
    #pragma unroll
    for (int p = 0; p < 8; ++p) {
        float4 o;
        o.x = ctx[p * 4 + 0] * inv;
        o.y = ctx[p * 4 + 1] * inv;
        o.z = ctx[p * 4 + 2] * inv;
        o.w = ctx[p * 4 + 3] * inv;
        *(float4*)(out + base + p * 4) = o;
    }
}

extern "C" void kernel_launch(void* const* d_in, const int* in_sizes, int n_in,
                              void* d_out, int out_size, void* d_ws, size_t ws_size,
                              hipStream_t stream) {
    const float* hs = (const float*)d_in[0];
    const float* wq = (const float*)d_in[1];
    const float* bq = (const float*)d_in[2];
    const float* wk = (const float*)d_in[3];
    const float* bk = (const float*)d_in[4];
    const float* wv = (const float*)d_in[5];
    const float* bv = (const float*)d_in[6];
    const float* rpb = (const float*)d_in[7];

    __hip_bfloat16* Q = (__hip_bfloat16*)d_ws;
    __hip_bfloat16* K = Q + (size_t)NPIX * DIM;
    __hip_bfloat16* V = K + (size_t)NPIX * DIM;

    dim3 pgrid(NPIX / 64, 3);
    proj_kernel<<<pgrid, 256, 0, stream>>>(hs, wq, wk, wv, bq, bk, bv, Q, K, V);

    nattn_kernel<<<(NPIX * HEADS) / 256, 256, 0, stream>>>(Q, K, V, rpb,
                                                           (float*)d_out);
}

// Round 4
// 54.479 us; speedup vs baseline: 2.4260x; 2.4260x over previous
//
#include <hip/hip_runtime.h>
#include <hip/hip_bf16.h>

typedef __attribute__((ext_vector_type(8))) short bf16x8;
typedef __attribute__((ext_vector_type(4))) float f32x4;

#define NPIX 6272          // 2*56*56
#define HW 56
#define HEADS 8
#define HD 32
#define KW 7
#define DIM 256
#define UK 112             // union keys: 8 rows x 14 cols
#define UKP 128            // padded keys

__device__ inline short f2bf(float f) {
    __hip_bfloat16 h = __float2bfloat16(f);
    return *(short*)&h;
}

// ---------------- Projection GEMM: Y = X @ W^T + b (optionally * scale) ----
// grid (98, 4, 3): 64-row x 64-col tiles; z selects q/k/v. W slice staged in
// LDS as swizzled bf16; A converted f32->bf16 inline (reused over 4 MFMAs).
__global__ __launch_bounds__(256) void proj_kernel(
    const float* __restrict__ X,
    const float* __restrict__ Wq, const float* __restrict__ Wk, const float* __restrict__ Wv,
    const float* __restrict__ Bq, const float* __restrict__ Bk, const float* __restrict__ Bv,
    __hip_bfloat16* __restrict__ Qo, __hip_bfloat16* __restrict__ Ko, __hip_bfloat16* __restrict__ Vo)
{
    __shared__ short Wsh[64 * 256];   // 32KB bf16, byte ^= ((col&31)<<4)

    const int tid  = threadIdx.x;
    const int wave = tid >> 6;
    const int lane = tid & 63;
    const int l15  = lane & 15;
    const int hi   = lane >> 4;

    const float* W; const float* Bi; __hip_bfloat16* Y; float scale;
    if (blockIdx.z == 0)      { W = Wq; Bi = Bq; Y = Qo; scale = 0.17677669529663687f; }
    else if (blockIdx.z == 1) { W = Wk; Bi = Bk; Y = Ko; scale = 1.0f; }
    else                      { W = Wv; Bi = Bv; Y = Vo; scale = 1.0f; }

    // stage W slice [64 cols][256 k] -> bf16 swizzled
    {
        const int col = tid >> 2;
        const int k0  = (tid & 3) * 64;
        const float* src = W + (size_t)(blockIdx.y * 64 + col) * DIM + k0;
        char* row = (char*)Wsh + col * 512;
        const int swz = (col & 31) << 4;
        #pragma unroll
        for (int m = 0; m < 8; ++m) {
            float4 f0 = *(const float4*)(src + m * 8);
            float4 f1 = *(const float4*)(src + m * 8 + 4);
            bf16x8 v;
            v[0]=f2bf(f0.x); v[1]=f2bf(f0.y); v[2]=f2bf(f0.z); v[3]=f2bf(f0.w);
            v[4]=f2bf(f1.x); v[5]=f2bf(f1.y); v[6]=f2bf(f1.z); v[7]=f2bf(f1.w);
            int d = k0 + m * 8;
            *(bf16x8*)(row + ((2 * d) ^ swz)) = v;
        }
    }
    __syncthreads();

    const int rowA = blockIdx.x * 64 + wave * 16 + l15;
    const float* xrow = X + (size_t)rowA * DIM;

    f32x4 acc[4];
    #pragma unroll
    for (int c = 0; c < 4; ++c) acc[c] = (f32x4){0.f, 0.f, 0.f, 0.f};

    #pragma unroll
    for (int kk = 0; kk < 8; ++kk) {
        float4 a0 = *(const float4*)(xrow + kk * 32 + hi * 8);
        float4 a1 = *(const float4*)(xrow + kk * 32 + hi * 8 + 4);
        bf16x8 a;
        a[0]=f2bf(a0.x); a[1]=f2bf(a0.y); a[2]=f2bf(a0.z); a[3]=f2bf(a0.w);
        a[4]=f2bf(a1.x); a[5]=f2bf(a1.y); a[6]=f2bf(a1.z); a[7]=f2bf(a1.w);
        #pragma unroll
        for (int c = 0; c < 4; ++c) {
            const int col = c * 16 + l15;
            bf16x8 b = *(const bf16x8*)((char*)Wsh + col * 512 +
                                        ((kk * 64 + hi * 16) ^ ((col & 31) << 4)));
            acc[c] = __builtin_amdgcn_mfma_f32_16x16x32_bf16(a, b, acc[c], 0, 0, 0);
        }
    }

    #pragma unroll
    for (int c = 0; c < 4; ++c) {
        const int col = blockIdx.y * 64 + c * 16 + l15;
        const float bvv = Bi[col];
        #pragma unroll
        for (int r = 0; r < 4; ++r) {
            const int row = blockIdx.x * 64 + wave * 16 + hi * 4 + r;
            Y[(size_t)row * DIM + col] = __float2bfloat16((acc[c][r] + bvv) * scale);
        }
    }
}

// ---------------- Neighborhood attention, MFMA-tiled -----------------------
// block = (jt, ip, b): 16 pixels = 2 rows x 8 cols; key union = 8x14 = 112.
// 4 waves; wave w does heads 2w, 2w+1. V gathered with scalar ds_read_u16
// (no ds_read_b64_tr_b16 — its semantics were the round-3 failure suspect).
__global__ __launch_bounds__(256) void nattn_kernel(
    const __hip_bfloat16* __restrict__ Qg,   // [NPIX][256] bf16 ws
    const __hip_bfloat16* __restrict__ Kg,
    const __hip_bfloat16* __restrict__ Vg,
    const float* __restrict__ rpb,           // [8][13][13] f32
    float* __restrict__ out)                 // [NPIX][256] f32
{
    __shared__ short Ksh[UK * 256];               // 57344 B, byte ^= ((key&31)<<4)
    __shared__ short Vsh[UKP * 256];              // 65536 B, same layout/swizzle
    __shared__ short Psh[4 * 16 * UKP];           // 16384 B, byte ^= (pix<<4)
    __shared__ float rpbs[HEADS * 169];           // 5408 B

    const int tid  = threadIdx.x;
    const int wv   = tid >> 6;
    const int lane = tid & 63;
    const int l15  = lane & 15;
    const int hi   = lane >> 4;

    const int jt = blockIdx.x;          // 0..6
    const int i0 = 2 * blockIdx.y;      // pixel row pair
    const int bz = blockIdx.z;
    const int j0 = jt * 8;
    const int r0 = min(max(i0 - 3, 0), HW - KW);
    const int c0 = min(max(j0 - 3, 0), HW - KW);

    // ---- staging ----
    for (int idx = tid; idx < HEADS * 169; idx += 256) rpbs[idx] = rpb[idx];

    {
        const int key = tid >> 1;            // 0..127
        const int dh  = tid & 1;             // 128-dim half
        const int a = key / 14, c = key - a * 14;
        const int gi = min(r0 + a, HW - 1), gj = min(c0 + c, HW - 1);
        const bool real = (key < UK);
        const short* srcK = (const short*)Kg + ((size_t)((bz * HW + gi) * HW + gj)) * DIM + dh * 128;
        const short* srcV = (const short*)Vg + ((size_t)((bz * HW + gi) * HW + gj)) * DIM + dh * 128;
        char* kshRow = (char*)Ksh + key * 512;
        char* vshRow = (char*)Vsh + key * 512;
        const int swz = (key & 31) << 4;
        #pragma unroll
        for (int m = 0; m < 16; ++m) {
            const int d = dh * 128 + m * 8;
            bf16x8 vv = {0,0,0,0,0,0,0,0};
            if (real) {
                bf16x8 kv = *(const bf16x8*)(srcK + m * 8);
                *(bf16x8*)(kshRow + ((2 * d) ^ swz)) = kv;
                vv = *(const bf16x8*)(srcV + m * 8);
            }
            *(bf16x8*)(vshRow + ((2 * d) ^ swz)) = vv;   // zero-fill fake keys
        }
    }
    {   // zero Psh keys 112..127 (swizzled addresses), per wave region
        const int p = (lane >> 2) & 15, m4 = lane & 3;
        const int k = UK + m4 * 4;
        char* dst = (char*)Psh + (wv * 16 + p) * 256 + ((2 * k) ^ (p << 4));
        *(int2*)dst = make_int2(0, 0);
    }
    __syncthreads();

    // per-lane pixel metadata for the 4 C-rows (pix = hi*4+r)
    int iv[4], jv[4], siv[4], sjv[4];
    #pragma unroll
    for (int r = 0; r < 4; ++r) {
        const int p = hi * 4 + r;
        iv[r] = i0 + (p >> 3);
        jv[r] = j0 + (p & 7);
        siv[r] = min(max(iv[r] - 3, 0), HW - KW);
        sjv[r] = min(max(jv[r] - 3, 0), HW - KW);
    }
    const f32x4 zf = {0.f, 0.f, 0.f, 0.f};

    for (int hh = 0; hh < 2; ++hh) {
        const int h = wv * 2 + hh;

        // A-frag: Q[pix l15][h*32 + hi*8 ..+7]
        const int p = l15;
        const int qpix = (bz * HW + i0 + (p >> 3)) * HW + j0 + (p & 7);
        bf16x8 aq = *(const bf16x8*)((const short*)Qg + (size_t)qpix * DIM + h * HD + hi * 8);

        // scores: 7 MFMA over key tiles
        f32x4 sacc[7];
        #pragma unroll
        for (int t = 0; t < 7; ++t) {
            const int key = t * 16 + l15;
            bf16x8 kb = *(const bf16x8*)((char*)Ksh + key * 512 +
                                         ((h * 64 + hi * 16) ^ ((key & 31) << 4)));
            sacc[t] = __builtin_amdgcn_mfma_f32_16x16x32_bf16(aq, kb, zf, 0, 0, 0);
        }

        // bias + mask -> sc[r][t]
        float sc[4][7];
        #pragma unroll
        for (int t = 0; t < 7; ++t) {
            const int key = t * 16 + l15;
            const int a = key / 14, c = key - a * 14;
            const int ki = r0 + a, kj = c0 + c;
            #pragma unroll
            for (int r = 0; r < 4; ++r) {
                const bool ok = (ki >= siv[r]) & (ki <= siv[r] + 6) &
                                (kj >= sjv[r]) & (kj <= sjv[r] + 6);
                const int bidx = ok ? ((ki - iv[r] + 6) * 13 + (kj - jv[r] + 6)) : 0;
                const float s = sacc[t][r] + rpbs[h * 169 + bidx];
                sc[r][t] = ok ? s : -1e30f;
            }
        }

        // row max (reduce over the 16 lanes of each l15 group)
        float mx[4], sm[4];
        #pragma unroll
        for (int r = 0; r < 4; ++r) {
            float m = sc[r][0];
            #pragma unroll
            for (int t = 1; t < 7; ++t) m = fmaxf(m, sc[r][t]);
            m = fmaxf(m, __shfl_xor(m, 1));
            m = fmaxf(m, __shfl_xor(m, 2));
            m = fmaxf(m, __shfl_xor(m, 4));
            m = fmaxf(m, __shfl_xor(m, 8));
            mx[r] = m;
        }
        // exp + store P (unnormalized bf16) + sum
        #pragma unroll
        for (int r = 0; r < 4; ++r) {
            const int pix = hi * 4 + r;
            char* prow = (char*)Psh + (wv * 16 + pix) * 256;
            const int pswz = pix << 4;
            float s = 0.f;
            #pragma unroll
            for (int t = 0; t < 7; ++t) {
                const float e = __expf(sc[r][t] - mx[r]);
                s += e;
                const int key = t * 16 + l15;
                *(short*)(prow + ((2 * key) ^ pswz)) = f2bf(e);
            }
            s += __shfl_xor(s, 1);
            s += __shfl_xor(s, 2);
            s += __shfl_xor(s, 4);
            s += __shfl_xor(s, 8);
            sm[r] = s;
        }

        // PV: 4 ksteps x 2 dim-tiles; V via scalar LDS gathers
        f32x4 o0 = zf, o1 = zf;
        #pragma unroll
        for (int kk = 0; kk < 4; ++kk) {
            bf16x8 pa = *(const bf16x8*)((char*)Psh + (wv * 16 + l15) * 256 +
                                         ((kk * 64 + hi * 16) ^ (l15 << 4)));
            bf16x8 vb0, vb1;
            #pragma unroll
            for (int e = 0; e < 8; ++e) {
                const int key = kk * 32 + hi * 8 + e;
                const char* vrow = (const char*)Vsh + key * 512;
                const int swz = (key & 31) << 4;
                vb0[e] = *(const short*)(vrow + ((h * 64 + 2 * l15) ^ swz));
                vb1[e] = *(const short*)(vrow + ((h * 64 + 32 + 2 * l15) ^ swz));
            }
            o0 = __builtin_amdgcn_mfma_f32_16x16x32_bf16(pa, vb0, o0, 0, 0, 0);
            o1 = __builtin_amdgcn_mfma_f32_16x16x32_bf16(pa, vb1, o1, 0, 0, 0);
        }

        // epilogue: apply 1/sum, store f32
        #pragma unroll
        for (int r = 0; r < 4; ++r) {
            const float inv = 1.f / sm[r];
            const int pg = (bz * HW + iv[r]) * HW + jv[r];
            out[(size_t)pg * DIM + h * HD + l15]      = o0[r] * inv;
            out[(size_t)pg * DIM + h * HD + 16 + l15] = o1[r] * inv;
        }
    }
}

extern "C" void kernel_launch(void* const* d_in, const int* in_sizes, int n_in,
                              void* d_out, int out_size, void* d_ws, size_t ws_size,
                              hipStream_t stream) {
    const float* hs = (const float*)d_in[0];
    const float* wq = (const float*)d_in[1];
    const float* bq = (const float*)d_in[2];
    const float* wk = (const float*)d_in[3];
    const float* bk = (const float*)d_in[4];
    const float* wv = (const float*)d_in[5];
    const float* bv = (const float*)d_in[6];
    const float* rpb = (const float*)d_in[7];

    __hip_bfloat16* Q = (__hip_bfloat16*)d_ws;
    __hip_bfloat16* K = Q + (size_t)NPIX * DIM;
    __hip_bfloat16* V = K + (size_t)NPIX * DIM;

    proj_kernel<<<dim3(NPIX / 64, 4, 3), 256, 0, stream>>>(hs, wq, wk, wv, bq, bk, bv, Q, K, V);

    nattn_kernel<<<dim3(7, 28, 2), 256, 0, stream>>>(Q, K, V, rpb, (float*)d_out);
}

// Round 5
// 41.883 us; speedup vs baseline: 3.1557x; 1.3008x over previous
//
#include <hip/hip_runtime.h>
#include <hip/hip_bf16.h>

typedef __attribute__((ext_vector_type(8))) short bf16x8;
typedef __attribute__((ext_vector_type(4))) float f32x4;

#define NPIX 6272          // 2*56*56
#define HW 56
#define HEADS 8
#define HD 32
#define KW 7
#define DIM 256
#define UK 112             // union keys: 8 rows x 14 cols
#define UKP 128            // padded keys
#define NX (NPIX * DIM)    // 1605632
#define NW (DIM * DIM)     // 65536

__device__ inline short f2bf(float f) {
    __hip_bfloat16 h = __float2bfloat16(f);
    return *(short*)&h;
}

// ---------------- f32 -> bf16 conversion pre-pass ---------------------------
// Converts X and the three W matrices once so proj is a pure bf16 GEMM.
__global__ __launch_bounds__(256) void cvt_kernel(
    const float* __restrict__ X,
    const float* __restrict__ Wq, const float* __restrict__ Wk, const float* __restrict__ Wv,
    short* __restrict__ Xb, short* __restrict__ Wqb,
    short* __restrict__ Wkb, short* __restrict__ Wvb)
{
    const size_t e0 = ((size_t)blockIdx.x * 256 + threadIdx.x) * 8;
    const float* src; short* dst; size_t off;
    if (e0 < NX)                { src = X;  dst = Xb;  off = e0; }
    else if (e0 < NX + NW)      { src = Wq; dst = Wqb; off = e0 - NX; }
    else if (e0 < NX + 2 * NW)  { src = Wk; dst = Wkb; off = e0 - NX - NW; }
    else                        { src = Wv; dst = Wvb; off = e0 - NX - 2 * NW; }
    float4 f0 = *(const float4*)(src + off);
    float4 f1 = *(const float4*)(src + off + 4);
    bf16x8 v;
    v[0]=f2bf(f0.x); v[1]=f2bf(f0.y); v[2]=f2bf(f0.z); v[3]=f2bf(f0.w);
    v[4]=f2bf(f1.x); v[5]=f2bf(f1.y); v[6]=f2bf(f1.z); v[7]=f2bf(f1.w);
    *(bf16x8*)(dst + off) = v;
}

// ---------------- Projection GEMM (bf16 in): Y = X @ W^T + b (* scale) ------
// grid (98, 4, 3). W slice staged in LDS swizzled; A-frags from global bf16.
__global__ __launch_bounds__(256) void proj_kernel(
    const short* __restrict__ Xb,
    const short* __restrict__ Wqb, const short* __restrict__ Wkb, const short* __restrict__ Wvb,
    const float* __restrict__ Bq, const float* __restrict__ Bk, const float* __restrict__ Bv,
    __hip_bfloat16* __restrict__ Qo, __hip_bfloat16* __restrict__ Ko, __hip_bfloat16* __restrict__ Vo)
{
    __shared__ short Wsh[64 * 256];   // 32KB, byte ^= ((col&31)<<4)

    const int tid  = threadIdx.x;
    const int wave = tid >> 6;
    const int lane = tid & 63;
    const int l15  = lane & 15;
    const int hi   = lane >> 4;

    const short* W; const float* Bi; __hip_bfloat16* Y; float scale;
    if (blockIdx.z == 0)      { W = Wqb; Bi = Bq; Y = Qo; scale = 0.17677669529663687f; }
    else if (blockIdx.z == 1) { W = Wkb; Bi = Bk; Y = Ko; scale = 1.0f; }
    else                      { W = Wvb; Bi = Bv; Y = Vo; scale = 1.0f; }

    {   // stage W slice [64 cols][256 k] swizzled (straight bf16 copy)
        const int col = tid >> 2;
        const int k0  = (tid & 3) * 64;
        const short* src = W + (size_t)(blockIdx.y * 64 + col) * DIM + k0;
        char* row = (char*)Wsh + col * 512;
        const int swz = (col & 31) << 4;
        #pragma unroll
        for (int m = 0; m < 8; ++m) {
            bf16x8 v = *(const bf16x8*)(src + m * 8);
            *(bf16x8*)(row + ((2 * (k0 + m * 8)) ^ swz)) = v;
        }
    }
    __syncthreads();

    const short* xrow = Xb + (size_t)(blockIdx.x * 64 + wave * 16 + l15) * DIM;

    f32x4 acc[4];
    #pragma unroll
    for (int c = 0; c < 4; ++c) acc[c] = (f32x4){0.f, 0.f, 0.f, 0.f};

    #pragma unroll
    for (int kk = 0; kk < 8; ++kk) {
        bf16x8 a = *(const bf16x8*)(xrow + kk * 32 + hi * 8);
        #pragma unroll
        for (int c = 0; c < 4; ++c) {
            const int col = c * 16 + l15;
            bf16x8 b = *(const bf16x8*)((char*)Wsh + col * 512 +
                                        ((kk * 64 + hi * 16) ^ ((col & 31) << 4)));
            acc[c] = __builtin_amdgcn_mfma_f32_16x16x32_bf16(a, b, acc[c], 0, 0, 0);
        }
    }

    #pragma unroll
    for (int c = 0; c < 4; ++c) {
        const int col = blockIdx.y * 64 + c * 16 + l15;
        const float bvv = Bi[col];
        #pragma unroll
        for (int r = 0; r < 4; ++r) {
            const int row = blockIdx.x * 64 + wave * 16 + hi * 4 + r;
            Y[(size_t)row * DIM + col] = __float2bfloat16((acc[c][r] + bvv) * scale);
        }
    }
}

// ---------------- Neighborhood attention, MFMA-tiled ------------------------
// block = (jt, ip, b): 16 pixels = 2 rows x 8 cols; key union = 8x14 = 112.
// 4 waves; wave w does heads 2w, 2w+1. K-frags + rpb straight from global
// (single-use / L1-hot). V staged TRANSPOSED in LDS -> PV is b128 + MFMA.
// LDS = 64K + 16K = 80KB -> 2 blocks/CU.
__global__ __launch_bounds__(256) void nattn_kernel(
    const __hip_bfloat16* __restrict__ Qg,   // [NPIX][256] bf16 ws
    const __hip_bfloat16* __restrict__ Kg,
    const __hip_bfloat16* __restrict__ Vg,
    const float* __restrict__ rpb,           // [8][13][13] f32
    float* __restrict__ out)                 // [NPIX][256] f32
{
    __shared__ short VshT[DIM * UKP];        // 65536 B: [dim][key], byte ^= ((d&7)<<4)
    __shared__ short Psh[4 * 16 * UKP];      // 16384 B: byte ^= (pix<<4)

    const int tid  = threadIdx.x;
    const int wv   = tid >> 6;
    const int lane = tid & 63;
    const int l15  = lane & 15;
    const int hi   = lane >> 4;

    const int jt = blockIdx.x;          // 0..6
    const int i0 = 2 * blockIdx.y;      // pixel row pair
    const int bz = blockIdx.z;
    const int j0 = jt * 8;
    const int r0 = min(max(i0 - 3, 0), HW - KW);
    const int c0 = min(max(j0 - 3, 0), HW - KW);

    // ---- stage V transposed: VshT[d][key] ----
    {
        const int key = tid >> 1;            // 0..127
        const int dh  = tid & 1;             // 128-dim half
        const int a = key / 14, c = key - a * 14;
        const int gi = min(r0 + a, HW - 1), gj = min(c0 + c, HW - 1);
        const bool real = (key < UK);
        const short* srcV = (const short*)Vg + ((size_t)((bz * HW + gi) * HW + gj)) * DIM + dh * 128;
        #pragma unroll
        for (int m = 0; m < 16; ++m) {
            const int d0 = dh * 128 + m * 8;
            bf16x8 vv = {0,0,0,0,0,0,0,0};
            if (real) vv = *(const bf16x8*)(srcV + m * 8);
            #pragma unroll
            for (int e = 0; e < 8; ++e) {
                const int d = d0 + e;        // d&7 == e
                *(short*)((char*)VshT + d * 256 + ((2 * key) ^ (e << 4))) = vv[e];
            }
        }
    }
    {   // zero Psh keys 112..127 (swizzled addresses), per wave region
        const int p = (lane >> 2) & 15, m4 = lane & 3;
        const int k = UK + m4 * 4;
        char* dst = (char*)Psh + (wv * 16 + p) * 256 + ((2 * k) ^ (p << 4));
        *(int2*)dst = make_int2(0, 0);
    }
    __syncthreads();

    // per-lane pixel metadata for the 4 C-rows (pix = hi*4+r)
    int iv[4], jv[4], siv[4], sjv[4];
    #pragma unroll
    for (int r = 0; r < 4; ++r) {
        const int p = hi * 4 + r;
        iv[r] = i0 + (p >> 3);
        jv[r] = j0 + (p & 7);
        siv[r] = min(max(iv[r] - 3, 0), HW - KW);
        sjv[r] = min(max(jv[r] - 3, 0), HW - KW);
    }
    const f32x4 zf = {0.f, 0.f, 0.f, 0.f};

    for (int hh = 0; hh < 2; ++hh) {
        const int h = wv * 2 + hh;

        // A-frag: Q[pix l15][h*32 + hi*8 ..+7]  (global)
        const int qpix = (bz * HW + i0 + (l15 >> 3)) * HW + j0 + (l15 & 7);
        bf16x8 aq = *(const bf16x8*)((const short*)Qg + (size_t)qpix * DIM + h * HD + hi * 8);

        // scores: 7 MFMA over key tiles; K B-frags straight from global
        f32x4 sacc[7];
        #pragma unroll
        for (int t = 0; t < 7; ++t) {
            const int key = t * 16 + l15;
            const int a = key / 14, c = key - a * 14;
            const int gi = min(r0 + a, HW - 1), gj = min(c0 + c, HW - 1);
            bf16x8 kb = *(const bf16x8*)((const short*)Kg +
                         ((size_t)((bz * HW + gi) * HW + gj)) * DIM + h * HD + hi * 8);
            sacc[t] = __builtin_amdgcn_mfma_f32_16x16x32_bf16(aq, kb, zf, 0, 0, 0);
        }

        // bias + mask -> sc[r][t]  (rpb from global, L1-hot)
        const float* rb = rpb + h * 169;
        float sc[4][7];
        #pragma unroll
        for (int t = 0; t < 7; ++t) {
            const int key = t * 16 + l15;
            const int a = key / 14, c = key - a * 14;
            const int ki = r0 + a, kj = c0 + c;
            #pragma unroll
            for (int r = 0; r < 4; ++r) {
                const bool ok = (ki >= siv[r]) & (ki <= siv[r] + 6) &
                                (kj >= sjv[r]) & (kj <= sjv[r] + 6);
                const int bidx = ok ? ((ki - iv[r] + 6) * 13 + (kj - jv[r] + 6)) : 0;
                const float s = sacc[t][r] + rb[bidx];
                sc[r][t] = ok ? s : -1e30f;
            }
        }

        // row max + exp + P store + sum (16-lane shfl reductions)
        float sm[4];
        #pragma unroll
        for (int r = 0; r < 4; ++r) {
            float m = sc[r][0];
            #pragma unroll
            for (int t = 1; t < 7; ++t) m = fmaxf(m, sc[r][t]);
            m = fmaxf(m, __shfl_xor(m, 1));
            m = fmaxf(m, __shfl_xor(m, 2));
            m = fmaxf(m, __shfl_xor(m, 4));
            m = fmaxf(m, __shfl_xor(m, 8));
            const int pix = hi * 4 + r;
            char* prow = (char*)Psh + (wv * 16 + pix) * 256;
            const int pswz = pix << 4;
            float s = 0.f;
            #pragma unroll
            for (int t = 0; t < 7; ++t) {
                const float e = __expf(sc[r][t] - m);
                s += e;
                const int key = t * 16 + l15;
                *(short*)(prow + ((2 * key) ^ pswz)) = f2bf(e);
            }
            s += __shfl_xor(s, 1);
            s += __shfl_xor(s, 2);
            s += __shfl_xor(s, 4);
            s += __shfl_xor(s, 8);
            sm[r] = s;
        }

        // PV: 4 ksteps x 2 dim-tiles; V via swizzled ds_read_b128 from VshT
        const int d0 = h * HD + l15;        // dim for o0 (d0&7 == l15&7)
        f32x4 o0 = zf, o1 = zf;
        #pragma unroll
        for (int kk = 0; kk < 4; ++kk) {
            bf16x8 pa = *(const bf16x8*)((char*)Psh + (wv * 16 + l15) * 256 +
                                         ((kk * 64 + hi * 16) ^ (l15 << 4)));
            const int koff = (kk * 64 + hi * 16) ^ ((l15 & 7) << 4);
            bf16x8 vb0 = *(const bf16x8*)((char*)VshT + d0 * 256 + koff);
            bf16x8 vb1 = *(const bf16x8*)((char*)VshT + (d0 + 16) * 256 + koff);
            o0 = __builtin_amdgcn_mfma_f32_16x16x32_bf16(pa, vb0, o0, 0, 0, 0);
            o1 = __builtin_amdgcn_mfma_f32_16x16x32_bf16(pa, vb1, o1, 0, 0, 0);
        }

        // epilogue: apply 1/sum, store f32
        #pragma unroll
        for (int r = 0; r < 4; ++r) {
            const float inv = 1.f / sm[r];
            const int pg = (bz * HW + iv[r]) * HW + jv[r];
            out[(size_t)pg * DIM + h * HD + l15]      = o0[r] * inv;
            out[(size_t)pg * DIM + h * HD + 16 + l15] = o1[r] * inv;
        }
    }
}

extern "C" void kernel_launch(void* const* d_in, const int* in_sizes, int n_in,
                              void* d_out, int out_size, void* d_ws, size_t ws_size,
                              hipStream_t stream) {
    const float* hs = (const float*)d_in[0];
    const float* wq = (const float*)d_in[1];
    const float* bq = (const float*)d_in[2];
    const float* wk = (const float*)d_in[3];
    const float* bk = (const float*)d_in[4];
    const float* wv = (const float*)d_in[5];
    const float* bv = (const float*)d_in[6];
    const float* rpb = (const float*)d_in[7];

    short* Q   = (short*)d_ws;
    short* K   = Q + (size_t)NX;
    short* V   = K + (size_t)NX;
    short* Xb  = V + (size_t)NX;
    short* Wqb = Xb + (size_t)NX;
    short* Wkb = Wqb + (size_t)NW;
    short* Wvb = Wkb + (size_t)NW;

    cvt_kernel<<<(NX + 3 * NW) / (256 * 8), 256, 0, stream>>>(hs, wq, wk, wv,
                                                              Xb, Wqb, Wkb, Wvb);

    proj_kernel<<<dim3(NPIX / 64, 4, 3), 256, 0, stream>>>(
        Xb, Wqb, Wkb, Wvb, bq, bk, bv,
        (__hip_bfloat16*)Q, (__hip_bfloat16*)K, (__hip_bfloat16*)V);

    nattn_kernel<<<dim3(7, 28, 2), 256, 0, stream>>>(
        (const __hip_bfloat16*)Q, (const __hip_bfloat16*)K, (const __hip_bfloat16*)V,
        rpb, (float*)d_out);
}